// Round 1
// baseline (664.308 us; speedup 1.0000x reference)
//
#include <hip/hip_runtime.h>
#include <hip/hip_bf16.h>
#include <stdint.h>

#define NN 100000
#define NE 1600000
#define NF 128

typedef __attribute__((ext_vector_type(8))) __bf16 bf16x8;
typedef __attribute__((ext_vector_type(4))) float floatx4;

static __device__ __forceinline__ unsigned short f2bf(float x) {
    union { float f; unsigned u; } v; v.f = x;
    unsigned r = v.u + 0x7fffu + ((v.u >> 16) & 1u);   // RNE
    return (unsigned short)(r >> 16);
}
static __device__ __forceinline__ float bflo(unsigned w) {
    union { unsigned u; float f; } v; v.u = w << 16; return v.f;
}
static __device__ __forceinline__ float bfhi(unsigned w) {
    union { unsigned u; float f; } v; v.u = w & 0xffff0000u; return v.f;
}

// fp32 -> bf16 (vectorized by 4)
__global__ void k_convert(const float* __restrict__ s, unsigned short* __restrict__ d, int n4) {
    int i = blockIdx.x * blockDim.x + threadIdx.x;
    if (i < n4) {
        float4 f = ((const float4*)s)[i];
        ushort4 o;
        o.x = f2bf(f.x); o.y = f2bf(f.y); o.z = f2bf(f.z); o.w = f2bf(f.w);
        ((ushort4*)d)[i] = o;
    }
}

__global__ void k_deg(const int* __restrict__ dst, int* __restrict__ deg, int n) {
    int i = blockIdx.x * blockDim.x + threadIdx.x;
    if (i < n) atomicAdd(&deg[dst[i]], 1);
}

// single-block exclusive scan over deg -> offs[0..NN], cursor = copy of offs
__global__ void k_scan(const int* __restrict__ deg, int* __restrict__ offs, int* __restrict__ cursor) {
    __shared__ int sh[1024];
    const int T = 1024;
    const int C = (NN + T - 1) / T;           // 98
    int t = threadIdx.x;
    int b = t * C;
    int e = b + C; if (e > NN) e = NN; if (b > NN) b = NN;
    int sum = 0;
    for (int i = b; i < e; ++i) sum += deg[i];
    sh[t] = sum;
    __syncthreads();
    for (int off = 1; off < T; off <<= 1) {
        int v = (t >= off) ? sh[t - off] : 0;
        __syncthreads();
        sh[t] += v;
        __syncthreads();
    }
    int run = sh[t] - sum;                     // exclusive prefix
    for (int i = b; i < e; ++i) {
        offs[i] = run; cursor[i] = run;
        run += deg[i];
    }
    if (t == T - 1) offs[NN] = run;
}

__global__ void k_scatter(const int* __restrict__ src, const int* __restrict__ dst,
                          int* __restrict__ cursor, int* __restrict__ csr, int n) {
    int i = blockIdx.x * blockDim.x + threadIdx.x;
    if (i < n) {
        int d = dst[i];
        int p = atomicAdd(&cursor[d], 1);
        csr[p] = src[i];
    }
}

// one wave per node: fp32 accumulate of bf16 feat rows, write bf16 agg row
__global__ void k_aggregate(const unsigned short* __restrict__ featb,
                            const int* __restrict__ offs,
                            const int* __restrict__ csr,
                            unsigned short* __restrict__ aggb) {
    int lane = threadIdx.x & 63;
    int node = blockIdx.x * 4 + (threadIdx.x >> 6);
    if (node >= NN) return;
    int s0 = offs[node], s1 = offs[node + 1];
    float a0 = 0.f, a1 = 0.f;
    for (int base = s0; base < s1; base += 64) {
        int e = (base + lane < s1) ? csr[base + lane] : 0;
        int m = s1 - base; if (m > 64) m = 64;
        int j = 0;
        for (; j + 4 <= m; j += 4) {                    // 4 loads in flight
            int n0 = __shfl(e, j, 64);
            int n1 = __shfl(e, j + 1, 64);
            int n2 = __shfl(e, j + 2, 64);
            int n3 = __shfl(e, j + 3, 64);
            unsigned w0 = *(const unsigned*)(featb + (size_t)n0 * NF + lane * 2);
            unsigned w1 = *(const unsigned*)(featb + (size_t)n1 * NF + lane * 2);
            unsigned w2 = *(const unsigned*)(featb + (size_t)n2 * NF + lane * 2);
            unsigned w3 = *(const unsigned*)(featb + (size_t)n3 * NF + lane * 2);
            a0 += bflo(w0) + bflo(w1) + bflo(w2) + bflo(w3);
            a1 += bfhi(w0) + bfhi(w1) + bfhi(w2) + bfhi(w3);
        }
        for (; j < m; ++j) {
            int nn = __shfl(e, j, 64);
            unsigned w = *(const unsigned*)(featb + (size_t)nn * NF + lane * 2);
            a0 += bflo(w); a1 += bfhi(w);
        }
    }
    unsigned outw = ((unsigned)f2bf(a1) << 16) | (unsigned)f2bf(a0);
    *(unsigned*)(aggb + (size_t)node * NF + lane * 2) = outw;
}

// fused dual GEMM + epilogue: out = relu(feat@Wv + norm*(agg@Wu) + bias)
// LDS: Wu,Wv transposed (Wt[n][k]) with XOR swizzle on 16B k-groups.
__global__ __launch_bounds__(256, 2) void k_gemm(
    const unsigned short* __restrict__ featb,   // [NN,128] bf16
    const unsigned short* __restrict__ aggb,    // [NN,128] bf16
    const unsigned short* __restrict__ wub,     // [128,128] bf16 row-major [k][n]
    const unsigned short* __restrict__ wvb,
    const float* __restrict__ bias,
    const int* __restrict__ deg,
    float* __restrict__ out) {
    __shared__ unsigned short lds[2 * 128 * 128];      // 64 KiB: [0..16383]=Wu^T, [16384..]=Wv^T
    for (int i = threadIdx.x; i < 128 * 128; i += 256) {
        int k = i >> 7, n = i & 127;
        int di = n * 128 + (((k >> 3) ^ (n & 7)) << 3) + (k & 7);
        lds[di]         = wub[i];
        lds[16384 + di] = wvb[i];
    }
    __syncthreads();

    int lane = threadIdx.x & 63;
    int wave = threadIdx.x >> 6;
    int quad = lane >> 4, l15 = lane & 15;
    int rb = blockIdx.x * 64 + wave * 16;
    int arow = rb + l15; if (arow > NN - 1) arow = NN - 1;

    const unsigned short* fr = featb + (size_t)arow * NF;
    const unsigned short* ar = aggb + (size_t)arow * NF;
    bf16x8 av[4], au[4];
#pragma unroll
    for (int ks = 0; ks < 4; ++ks) {
        av[ks] = *(const bf16x8*)(fr + ks * 32 + quad * 8);
        au[ks] = *(const bf16x8*)(ar + ks * 32 + quad * 8);
    }

    floatx4 accv[8], accu[8];
#pragma unroll
    for (int ct = 0; ct < 8; ++ct) {
        accv[ct] = (floatx4){0.f, 0.f, 0.f, 0.f};
        accu[ct] = (floatx4){0.f, 0.f, 0.f, 0.f};
    }

#pragma unroll
    for (int ct = 0; ct < 8; ++ct) {
        int n = ct * 16 + l15;
#pragma unroll
        for (int ks = 0; ks < 4; ++ks) {
            int k8 = ks * 4 + quad;
            int di = n * 128 + ((k8 ^ (n & 7)) << 3);
            bf16x8 bu = *(const bf16x8*)(&lds[di]);
            bf16x8 bv = *(const bf16x8*)(&lds[16384 + di]);
            accu[ct] = __builtin_amdgcn_mfma_f32_16x16x32_bf16(au[ks], bu, accu[ct], 0, 0, 0);
            accv[ct] = __builtin_amdgcn_mfma_f32_16x16x32_bf16(av[ks], bv, accv[ct], 0, 0, 0);
        }
    }

    float norm[4];
#pragma unroll
    for (int r = 0; r < 4; ++r) {
        int row = rb + quad * 4 + r;
        int dg = (row < NN) ? deg[row] : 1;
        if (dg < 1) dg = 1;
        norm[r] = 1.0f / (float)dg;
    }
#pragma unroll
    for (int ct = 0; ct < 8; ++ct) {
        int col = ct * 16 + l15;
        float bs = bias[col];
#pragma unroll
        for (int r = 0; r < 4; ++r) {
            int row = rb + quad * 4 + r;
            if (row < NN) {
                float v = accv[ct][r] + norm[r] * accu[ct][r] + bs;
                out[(size_t)row * NF + col] = v > 0.f ? v : 0.f;
            }
        }
    }
}

extern "C" void kernel_launch(void* const* d_in, const int* in_sizes, int n_in,
                              void* d_out, int out_size, void* d_ws, size_t ws_size,
                              hipStream_t stream) {
    const float* feat = (const float*)d_in[0];
    const float* wu   = (const float*)d_in[1];
    const float* wv   = (const float*)d_in[2];
    const float* bias = (const float*)d_in[3];
    const int* src    = (const int*)d_in[4];
    const int* dst    = (const int*)d_in[5];
    float* out        = (float*)d_out;

    char* ws = (char*)d_ws;
    int* deg              = (int*)(ws + 0);                 //   400,000 B
    int* offs             = (int*)(ws + 400384);            //   400,004 B
    int* cursor           = (int*)(ws + 800768);            //   400,000 B
    int* csr              = (int*)(ws + 1201152);           // 6,400,000 B
    unsigned short* featb = (unsigned short*)(ws + 7601152);   // 25,600,000 B
    unsigned short* aggb  = (unsigned short*)(ws + 33201152);  // 25,600,000 B
    unsigned short* wub   = (unsigned short*)(ws + 58801152);  //    32,768 B
    unsigned short* wvb   = (unsigned short*)(ws + 58833920);  //    32,768 B

    hipMemsetAsync(deg, 0, NN * sizeof(int), stream);

    k_convert<<<(NN * NF / 4 + 255) / 256, 256, 0, stream>>>(feat, featb, NN * NF / 4);
    k_convert<<<16, 256, 0, stream>>>(wu, wub, 128 * 128 / 4);
    k_convert<<<16, 256, 0, stream>>>(wv, wvb, 128 * 128 / 4);

    k_deg<<<(NE + 255) / 256, 256, 0, stream>>>(dst, deg, NE);
    k_scan<<<1, 1024, 0, stream>>>(deg, offs, cursor);
    k_scatter<<<(NE + 255) / 256, 256, 0, stream>>>(src, dst, cursor, csr, NE);
    k_aggregate<<<(NN + 3) / 4, 256, 0, stream>>>(featb, offs, csr, aggb);
    k_gemm<<<(NN + 63) / 64, 256, 0, stream>>>(featb, aggb, wub, wvb, bias, deg, out);
}

// Round 2
// 458.560 us; speedup vs baseline: 1.4487x; 1.4487x over previous
//
#include <hip/hip_runtime.h>
#include <hip/hip_bf16.h>
#include <stdint.h>

#define NN 100000
#define NE 1600000
#define NF 128
#define SCAN_B ((NN + 255) / 256)   // 391 blocks

typedef __attribute__((ext_vector_type(8))) __bf16 bf16x8;
typedef __attribute__((ext_vector_type(4))) float floatx4;

static __device__ __forceinline__ unsigned short f2bf(float x) {
    union { float f; unsigned u; } v; v.f = x;
    unsigned r = v.u + 0x7fffu + ((v.u >> 16) & 1u);   // RNE
    return (unsigned short)(r >> 16);
}
static __device__ __forceinline__ float bflo(unsigned w) {
    union { unsigned u; float f; } v; v.u = w << 16; return v.f;
}
static __device__ __forceinline__ float bfhi(unsigned w) {
    union { unsigned u; float f; } v; v.u = w & 0xffff0000u; return v.f;
}

// fp32 -> bf16 (vectorized by 4)
__global__ void k_convert(const float* __restrict__ s, unsigned short* __restrict__ d, int n4) {
    int i = blockIdx.x * blockDim.x + threadIdx.x;
    if (i < n4) {
        float4 f = ((const float4*)s)[i];
        ushort4 o;
        o.x = f2bf(f.x); o.y = f2bf(f.y); o.z = f2bf(f.z); o.w = f2bf(f.w);
        ((ushort4*)d)[i] = o;
    }
}

__global__ void k_deg(const int* __restrict__ dst, int* __restrict__ deg, int n) {
    int i = blockIdx.x * blockDim.x + threadIdx.x;
    if (i < n) atomicAdd(&deg[dst[i]], 1);
}

// phase A: per-block exclusive scan of 256 elements; emit block sums
__global__ void k_scan_a(const int* __restrict__ deg, int* __restrict__ offs,
                         int* __restrict__ bsums) {
    __shared__ int sh[256];
    int i = blockIdx.x * 256 + threadIdx.x;
    int v = (i < NN) ? deg[i] : 0;
    sh[threadIdx.x] = v;
    __syncthreads();
    for (int off = 1; off < 256; off <<= 1) {
        int u = (threadIdx.x >= off) ? sh[threadIdx.x - off] : 0;
        __syncthreads();
        sh[threadIdx.x] += u;
        __syncthreads();
    }
    if (i < NN) offs[i] = sh[threadIdx.x] - v;          // exclusive within block
    if (threadIdx.x == 255) bsums[blockIdx.x] = sh[255];
}

// phase B: single-block exclusive scan of the 391 block sums (fits one block)
__global__ void k_scan_b(int* __restrict__ bsums) {
    __shared__ int sh[512];
    int t = threadIdx.x;
    int v = (t < SCAN_B) ? bsums[t] : 0;
    sh[t] = v;
    __syncthreads();
    for (int off = 1; off < 512; off <<= 1) {
        int u = (t >= off) ? sh[t - off] : 0;
        __syncthreads();
        sh[t] += u;
        __syncthreads();
    }
    if (t < SCAN_B) bsums[t] = sh[t] - v;               // exclusive
    if (t == SCAN_B - 1) bsums[SCAN_B] = sh[t];         // total (= NE)
}

// phase C: add block prefix, materialize offs + cursor
__global__ void k_scan_c(int* __restrict__ offs, int* __restrict__ cursor,
                         const int* __restrict__ bsums) {
    int i = blockIdx.x * 256 + threadIdx.x;
    if (i < NN) {
        int o = offs[i] + bsums[blockIdx.x];
        offs[i] = o;
        cursor[i] = o;
    }
    if (i == NN - 1) offs[NN] = bsums[SCAN_B];
}

__global__ void k_scatter(const int* __restrict__ src, const int* __restrict__ dst,
                          int* __restrict__ cursor, int* __restrict__ csr, int n) {
    int i = blockIdx.x * blockDim.x + threadIdx.x;
    if (i < n) {
        int d = dst[i];
        int p = atomicAdd(&cursor[d], 1);
        csr[p] = src[i];
    }
}

// one wave per node: fp32 accumulate of bf16 feat rows, write bf16 agg row
__global__ void k_aggregate(const unsigned short* __restrict__ featb,
                            const int* __restrict__ offs,
                            const int* __restrict__ csr,
                            unsigned short* __restrict__ aggb) {
    int lane = threadIdx.x & 63;
    int node = blockIdx.x * 4 + (threadIdx.x >> 6);
    if (node >= NN) return;
    int s0 = offs[node], s1 = offs[node + 1];
    float a0 = 0.f, a1 = 0.f;
    for (int base = s0; base < s1; base += 64) {
        int e = (base + lane < s1) ? csr[base + lane] : 0;
        int m = s1 - base; if (m > 64) m = 64;
        int j = 0;
        for (; j + 4 <= m; j += 4) {                    // 4 loads in flight
            int n0 = __shfl(e, j, 64);
            int n1 = __shfl(e, j + 1, 64);
            int n2 = __shfl(e, j + 2, 64);
            int n3 = __shfl(e, j + 3, 64);
            unsigned w0 = *(const unsigned*)(featb + (size_t)n0 * NF + lane * 2);
            unsigned w1 = *(const unsigned*)(featb + (size_t)n1 * NF + lane * 2);
            unsigned w2 = *(const unsigned*)(featb + (size_t)n2 * NF + lane * 2);
            unsigned w3 = *(const unsigned*)(featb + (size_t)n3 * NF + lane * 2);
            a0 += bflo(w0) + bflo(w1) + bflo(w2) + bflo(w3);
            a1 += bfhi(w0) + bfhi(w1) + bfhi(w2) + bfhi(w3);
        }
        for (; j < m; ++j) {
            int nn = __shfl(e, j, 64);
            unsigned w = *(const unsigned*)(featb + (size_t)nn * NF + lane * 2);
            a0 += bflo(w); a1 += bfhi(w);
        }
    }
    unsigned outw = ((unsigned)f2bf(a1) << 16) | (unsigned)f2bf(a0);
    *(unsigned*)(aggb + (size_t)node * NF + lane * 2) = outw;
}

// fused dual GEMM + epilogue: out = relu(feat@Wv + norm*(agg@Wu) + bias)
// LDS: Wu,Wv transposed (Wt[n][k]) with XOR swizzle on 16B k-groups.
__global__ __launch_bounds__(256, 2) void k_gemm(
    const unsigned short* __restrict__ featb,   // [NN,128] bf16
    const unsigned short* __restrict__ aggb,    // [NN,128] bf16
    const unsigned short* __restrict__ wub,     // [128,128] bf16 row-major [k][n]
    const unsigned short* __restrict__ wvb,
    const float* __restrict__ bias,
    const int* __restrict__ deg,
    float* __restrict__ out) {
    __shared__ unsigned short lds[2 * 128 * 128];      // 64 KiB: [0..16383]=Wu^T, [16384..]=Wv^T
    for (int i = threadIdx.x; i < 128 * 128; i += 256) {
        int k = i >> 7, n = i & 127;
        int di = n * 128 + (((k >> 3) ^ (n & 7)) << 3) + (k & 7);
        lds[di]         = wub[i];
        lds[16384 + di] = wvb[i];
    }
    __syncthreads();

    int lane = threadIdx.x & 63;
    int wave = threadIdx.x >> 6;
    int quad = lane >> 4, l15 = lane & 15;
    int rb = blockIdx.x * 64 + wave * 16;
    int arow = rb + l15; if (arow > NN - 1) arow = NN - 1;

    const unsigned short* fr = featb + (size_t)arow * NF;
    const unsigned short* ar = aggb + (size_t)arow * NF;
    bf16x8 av[4], au[4];
#pragma unroll
    for (int ks = 0; ks < 4; ++ks) {
        av[ks] = *(const bf16x8*)(fr + ks * 32 + quad * 8);
        au[ks] = *(const bf16x8*)(ar + ks * 32 + quad * 8);
    }

    floatx4 accv[8], accu[8];
#pragma unroll
    for (int ct = 0; ct < 8; ++ct) {
        accv[ct] = (floatx4){0.f, 0.f, 0.f, 0.f};
        accu[ct] = (floatx4){0.f, 0.f, 0.f, 0.f};
    }

#pragma unroll
    for (int ct = 0; ct < 8; ++ct) {
        int n = ct * 16 + l15;
#pragma unroll
        for (int ks = 0; ks < 4; ++ks) {
            int k8 = ks * 4 + quad;
            int di = n * 128 + ((k8 ^ (n & 7)) << 3);
            bf16x8 bu = *(const bf16x8*)(&lds[di]);
            bf16x8 bv = *(const bf16x8*)(&lds[16384 + di]);
            accu[ct] = __builtin_amdgcn_mfma_f32_16x16x32_bf16(au[ks], bu, accu[ct], 0, 0, 0);
            accv[ct] = __builtin_amdgcn_mfma_f32_16x16x32_bf16(av[ks], bv, accv[ct], 0, 0, 0);
        }
    }

    float norm[4];
#pragma unroll
    for (int r = 0; r < 4; ++r) {
        int row = rb + quad * 4 + r;
        int dg = (row < NN) ? deg[row] : 1;
        if (dg < 1) dg = 1;
        norm[r] = 1.0f / (float)dg;
    }
#pragma unroll
    for (int ct = 0; ct < 8; ++ct) {
        int col = ct * 16 + l15;
        float bs = bias[col];
#pragma unroll
        for (int r = 0; r < 4; ++r) {
            int row = rb + quad * 4 + r;
            if (row < NN) {
                float v = accv[ct][r] + norm[r] * accu[ct][r] + bs;
                out[(size_t)row * NF + col] = v > 0.f ? v : 0.f;
            }
        }
    }
}

extern "C" void kernel_launch(void* const* d_in, const int* in_sizes, int n_in,
                              void* d_out, int out_size, void* d_ws, size_t ws_size,
                              hipStream_t stream) {
    const float* feat = (const float*)d_in[0];
    const float* wu   = (const float*)d_in[1];
    const float* wv   = (const float*)d_in[2];
    const float* bias = (const float*)d_in[3];
    const int* src    = (const int*)d_in[4];
    const int* dst    = (const int*)d_in[5];
    float* out        = (float*)d_out;

    char* ws = (char*)d_ws;
    int* deg              = (int*)(ws + 0);                 //   400,000 B
    int* offs             = (int*)(ws + 400384);            //   400,004 B
    int* cursor           = (int*)(ws + 800768);            //   400,000 B
    int* csr              = (int*)(ws + 1201152);           // 6,400,000 B
    unsigned short* featb = (unsigned short*)(ws + 7601152);   // 25,600,000 B
    unsigned short* aggb  = (unsigned short*)(ws + 33201152);  // 25,600,000 B
    unsigned short* wub   = (unsigned short*)(ws + 58801152);  //    32,768 B
    unsigned short* wvb   = (unsigned short*)(ws + 58833920);  //    32,768 B
    // bsums aliases aggb's region: dead before k_aggregate writes aggb
    int* bsums            = (int*)aggb;                     // (SCAN_B+1) ints

    hipMemsetAsync(deg, 0, NN * sizeof(int), stream);

    k_convert<<<(NN * NF / 4 + 255) / 256, 256, 0, stream>>>(feat, featb, NN * NF / 4);
    k_convert<<<16, 256, 0, stream>>>(wu, wub, 128 * 128 / 4);
    k_convert<<<16, 256, 0, stream>>>(wv, wvb, 128 * 128 / 4);

    k_deg<<<(NE + 255) / 256, 256, 0, stream>>>(dst, deg, NE);
    k_scan_a<<<SCAN_B, 256, 0, stream>>>(deg, offs, bsums);
    k_scan_b<<<1, 512, 0, stream>>>(bsums);
    k_scan_c<<<SCAN_B, 256, 0, stream>>>(offs, cursor, bsums);
    k_scatter<<<(NE + 255) / 256, 256, 0, stream>>>(src, dst, cursor, csr, NE);
    k_aggregate<<<(NN + 3) / 4, 256, 0, stream>>>(featb, offs, csr, aggb);
    k_gemm<<<(NN + 63) / 64, 256, 0, stream>>>(featb, aggb, wub, wvb, bias, deg, out);
}

// Round 4
// 425.873 us; speedup vs baseline: 1.5599x; 1.0768x over previous
//
#include <hip/hip_runtime.h>
#include <hip/hip_bf16.h>
#include <stdint.h>

#define NN 100000
#define NE 1600000
#define NF 128
#define SCAN_B ((NN + 255) / 256)   // 391 blocks
#define NGRP 8
#define GSZ (NN / NGRP)             // 12500 exactly
#define BPG 128                     // blocks per group

typedef __attribute__((ext_vector_type(8))) __bf16 bf16x8;
typedef __attribute__((ext_vector_type(4))) float floatx4;
typedef __attribute__((ext_vector_type(4))) unsigned short ushortx4;

static __device__ __forceinline__ unsigned short f2bf(float x) {
    union { float f; unsigned u; } v; v.f = x;
    unsigned r = v.u + 0x7fffu + ((v.u >> 16) & 1u);   // RNE
    return (unsigned short)(r >> 16);
}
static __device__ __forceinline__ float bflo(unsigned w) {
    union { unsigned u; float f; } v; v.u = w << 16; return v.f;
}
static __device__ __forceinline__ float bfhi(unsigned w) {
    union { unsigned u; float f; } v; v.u = w & 0xffff0000u; return v.f;
}

// fp32 -> bf16 (vectorized by 4)
__global__ void k_convert(const float* __restrict__ s, unsigned short* __restrict__ d, int n4) {
    int i = blockIdx.x * blockDim.x + threadIdx.x;
    if (i < n4) {
        floatx4 f = __builtin_nontemporal_load((const floatx4*)s + i);
        ushortx4 o;
        o.x = f2bf(f.x); o.y = f2bf(f.y); o.z = f2bf(f.z); o.w = f2bf(f.w);
        __builtin_nontemporal_store(o, (ushortx4*)d + i);
    }
}

// degree count, dst-range partitioned: blocks with blockIdx%8==g count only
// nodes in [g*GSZ,(g+1)*GSZ) -> atomics stay in one XCD's L2 slice (50 KB)
__global__ void k_deg(const int* __restrict__ dst, int* __restrict__ deg) {
    int base = (blockIdx.x & (NGRP - 1)) * GSZ;
    int tid = (blockIdx.x >> 3) * 256 + threadIdx.x;
    for (int i = tid; i < NE; i += BPG * 256) {
        int d = __builtin_nontemporal_load(&dst[i]);
        if ((unsigned)(d - base) < (unsigned)GSZ) atomicAdd(&deg[d], 1);
    }
}

// phase A: per-block exclusive scan of 256 elements; emit block sums
__global__ void k_scan_a(const int* __restrict__ deg, int* __restrict__ offs,
                         int* __restrict__ bsums) {
    __shared__ int sh[256];
    int i = blockIdx.x * 256 + threadIdx.x;
    int v = (i < NN) ? deg[i] : 0;
    sh[threadIdx.x] = v;
    __syncthreads();
    for (int off = 1; off < 256; off <<= 1) {
        int u = (threadIdx.x >= off) ? sh[threadIdx.x - off] : 0;
        __syncthreads();
        sh[threadIdx.x] += u;
        __syncthreads();
    }
    if (i < NN) offs[i] = sh[threadIdx.x] - v;          // exclusive within block
    if (threadIdx.x == 255) bsums[blockIdx.x] = sh[255];
}

// phase B: single-block exclusive scan of the 391 block sums
__global__ void k_scan_b(int* __restrict__ bsums) {
    __shared__ int sh[512];
    int t = threadIdx.x;
    int v = (t < SCAN_B) ? bsums[t] : 0;
    sh[t] = v;
    __syncthreads();
    for (int off = 1; off < 512; off <<= 1) {
        int u = (t >= off) ? sh[t - off] : 0;
        __syncthreads();
        sh[t] += u;
        __syncthreads();
    }
    if (t < SCAN_B) bsums[t] = sh[t] - v;               // exclusive
    if (t == SCAN_B - 1) bsums[SCAN_B] = sh[t];         // total (= NE)
}

// phase C: add block prefix, materialize offs + cursor
__global__ void k_scan_c(int* __restrict__ offs, int* __restrict__ cursor,
                         const int* __restrict__ bsums) {
    int i = blockIdx.x * 256 + threadIdx.x;
    if (i < NN) {
        int o = offs[i] + bsums[blockIdx.x];
        offs[i] = o;
        cursor[i] = o;
    }
    if (i == NN - 1) offs[NN] = bsums[SCAN_B];
}

// CSR scatter, dst-range partitioned for L2-local writes (kills the 16x
// write amplification seen in R2: WRITE_SIZE 105 MB for a 6.4 MB array)
__global__ void k_scatter(const int* __restrict__ src, const int* __restrict__ dst,
                          int* __restrict__ cursor, int* __restrict__ csr) {
    int base = (blockIdx.x & (NGRP - 1)) * GSZ;
    int tid = (blockIdx.x >> 3) * 256 + threadIdx.x;
    for (int i = tid; i < NE; i += BPG * 256) {
        int d = __builtin_nontemporal_load(&dst[i]);
        if ((unsigned)(d - base) < (unsigned)GSZ) {
            int s = __builtin_nontemporal_load(&src[i]);
            int p = atomicAdd(&cursor[d], 1);
            csr[p] = s;
        }
    }
}

// one wave per node: fp32 accumulate of bf16 feat rows, write bf16 agg row
__global__ void k_aggregate(const unsigned short* __restrict__ featb,
                            const int* __restrict__ offs,
                            const int* __restrict__ csr,
                            unsigned short* __restrict__ aggb) {
    int lane = threadIdx.x & 63;
    int node = blockIdx.x * 4 + (threadIdx.x >> 6);
    if (node >= NN) return;
    int s0 = offs[node], s1 = offs[node + 1];
    float a0 = 0.f, a1 = 0.f;
    for (int base = s0; base < s1; base += 64) {
        int e = (base + lane < s1) ? csr[base + lane] : 0;
        int m = s1 - base; if (m > 64) m = 64;
        int j = 0;
        for (; j + 8 <= m; j += 8) {                    // 8 loads in flight
            unsigned w0 = *(const unsigned*)(featb + (size_t)__shfl(e, j + 0, 64) * NF + lane * 2);
            unsigned w1 = *(const unsigned*)(featb + (size_t)__shfl(e, j + 1, 64) * NF + lane * 2);
            unsigned w2 = *(const unsigned*)(featb + (size_t)__shfl(e, j + 2, 64) * NF + lane * 2);
            unsigned w3 = *(const unsigned*)(featb + (size_t)__shfl(e, j + 3, 64) * NF + lane * 2);
            unsigned w4 = *(const unsigned*)(featb + (size_t)__shfl(e, j + 4, 64) * NF + lane * 2);
            unsigned w5 = *(const unsigned*)(featb + (size_t)__shfl(e, j + 5, 64) * NF + lane * 2);
            unsigned w6 = *(const unsigned*)(featb + (size_t)__shfl(e, j + 6, 64) * NF + lane * 2);
            unsigned w7 = *(const unsigned*)(featb + (size_t)__shfl(e, j + 7, 64) * NF + lane * 2);
            a0 += bflo(w0) + bflo(w1) + bflo(w2) + bflo(w3)
                + bflo(w4) + bflo(w5) + bflo(w6) + bflo(w7);
            a1 += bfhi(w0) + bfhi(w1) + bfhi(w2) + bfhi(w3)
                + bfhi(w4) + bfhi(w5) + bfhi(w6) + bfhi(w7);
        }
        for (; j < m; ++j) {
            int nn = __shfl(e, j, 64);
            unsigned w = *(const unsigned*)(featb + (size_t)nn * NF + lane * 2);
            a0 += bflo(w); a1 += bfhi(w);
        }
    }
    unsigned outw = ((unsigned)f2bf(a1) << 16) | (unsigned)f2bf(a0);
    *(unsigned*)(aggb + (size_t)node * NF + lane * 2) = outw;
}

// fused dual GEMM + epilogue: out = relu(feat@Wv + norm*(agg@Wu) + bias)
__global__ __launch_bounds__(256, 2) void k_gemm(
    const unsigned short* __restrict__ featb,   // [NN,128] bf16
    const unsigned short* __restrict__ aggb,    // [NN,128] bf16
    const unsigned short* __restrict__ wub,     // [128,128] bf16 row-major [k][n]
    const unsigned short* __restrict__ wvb,
    const float* __restrict__ bias,
    const int* __restrict__ deg,
    float* __restrict__ out) {
    __shared__ unsigned short lds[2 * 128 * 128];      // 64 KiB: Wu^T then Wv^T
    for (int i = threadIdx.x; i < 128 * 128; i += 256) {
        int k = i >> 7, n = i & 127;
        int di = n * 128 + (((k >> 3) ^ (n & 7)) << 3) + (k & 7);
        lds[di]         = wub[i];
        lds[16384 + di] = wvb[i];
    }
    __syncthreads();

    int lane = threadIdx.x & 63;
    int wave = threadIdx.x >> 6;
    int quad = lane >> 4, l15 = lane & 15;
    int rb = blockIdx.x * 64 + wave * 16;
    int arow = rb + l15; if (arow > NN - 1) arow = NN - 1;

    const unsigned short* fr = featb + (size_t)arow * NF;
    const unsigned short* ar = aggb + (size_t)arow * NF;
    bf16x8 av[4], au[4];
#pragma unroll
    for (int ks = 0; ks < 4; ++ks) {
        av[ks] = *(const bf16x8*)(fr + ks * 32 + quad * 8);
        au[ks] = *(const bf16x8*)(ar + ks * 32 + quad * 8);
    }

    floatx4 accv[8], accu[8];
#pragma unroll
    for (int ct = 0; ct < 8; ++ct) {
        accv[ct] = (floatx4){0.f, 0.f, 0.f, 0.f};
        accu[ct] = (floatx4){0.f, 0.f, 0.f, 0.f};
    }

#pragma unroll
    for (int ct = 0; ct < 8; ++ct) {
        int n = ct * 16 + l15;
#pragma unroll
        for (int ks = 0; ks < 4; ++ks) {
            int k8 = ks * 4 + quad;
            int di = n * 128 + ((k8 ^ (n & 7)) << 3);
            bf16x8 bu = *(const bf16x8*)(&lds[di]);
            bf16x8 bv = *(const bf16x8*)(&lds[16384 + di]);
            accu[ct] = __builtin_amdgcn_mfma_f32_16x16x32_bf16(au[ks], bu, accu[ct], 0, 0, 0);
            accv[ct] = __builtin_amdgcn_mfma_f32_16x16x32_bf16(av[ks], bv, accv[ct], 0, 0, 0);
        }
    }

    float norm[4];
#pragma unroll
    for (int r = 0; r < 4; ++r) {
        int row = rb + quad * 4 + r;
        int dg = (row < NN) ? deg[row] : 1;
        if (dg < 1) dg = 1;
        norm[r] = 1.0f / (float)dg;
    }
#pragma unroll
    for (int ct = 0; ct < 8; ++ct) {
        int col = ct * 16 + l15;
        float bs = bias[col];
#pragma unroll
        for (int r = 0; r < 4; ++r) {
            int row = rb + quad * 4 + r;
            if (row < NN) {
                float v = accv[ct][r] + norm[r] * accu[ct][r] + bs;
                out[(size_t)row * NF + col] = v > 0.f ? v : 0.f;
            }
        }
    }
}

extern "C" void kernel_launch(void* const* d_in, const int* in_sizes, int n_in,
                              void* d_out, int out_size, void* d_ws, size_t ws_size,
                              hipStream_t stream) {
    const float* feat = (const float*)d_in[0];
    const float* wu   = (const float*)d_in[1];
    const float* wv   = (const float*)d_in[2];
    const float* bias = (const float*)d_in[3];
    const int* src    = (const int*)d_in[4];
    const int* dst    = (const int*)d_in[5];
    float* out        = (float*)d_out;

    char* ws = (char*)d_ws;
    int* deg              = (int*)(ws + 0);                 //   400,000 B
    int* offs             = (int*)(ws + 400384);            //   400,004 B
    int* cursor           = (int*)(ws + 800768);            //   400,000 B
    int* csr              = (int*)(ws + 1201152);           // 6,400,000 B
    unsigned short* featb = (unsigned short*)(ws + 7601152);   // 25,600,000 B
    unsigned short* aggb  = (unsigned short*)(ws + 33201152);  // 25,600,000 B
    unsigned short* wub   = (unsigned short*)(ws + 58801152);  //    32,768 B
    unsigned short* wvb   = (unsigned short*)(ws + 58833920);  //    32,768 B
    // bsums aliases aggb's region: dead before k_aggregate writes aggb
    int* bsums            = (int*)aggb;                     // (SCAN_B+1) ints

    hipMemsetAsync(deg, 0, NN * sizeof(int), stream);

    k_convert<<<(NN * NF / 4 + 255) / 256, 256, 0, stream>>>(feat, featb, NN * NF / 4);
    k_convert<<<16, 256, 0, stream>>>(wu, wub, 128 * 128 / 4);
    k_convert<<<16, 256, 0, stream>>>(wv, wvb, 128 * 128 / 4);

    k_deg<<<NGRP * BPG, 256, 0, stream>>>(dst, deg);
    k_scan_a<<<SCAN_B, 256, 0, stream>>>(deg, offs, bsums);
    k_scan_b<<<1, 512, 0, stream>>>(bsums);
    k_scan_c<<<SCAN_B, 256, 0, stream>>>(offs, cursor, bsums);
    k_scatter<<<NGRP * BPG, 256, 0, stream>>>(src, dst, cursor, csr);
    k_aggregate<<<(NN + 3) / 4, 256, 0, stream>>>(featb, offs, csr, aggb);
    k_gemm<<<(NN + 63) / 64, 256, 0, stream>>>(featb, aggb, wub, wvb, bias, deg, out);
}

// Round 5
// 378.387 us; speedup vs baseline: 1.7556x; 1.1255x over previous
//
#include <hip/hip_runtime.h>
#include <hip/hip_bf16.h>
#include <stdint.h>

#define NN 100000
#define NE 1600000
#define NF 128
#define SCAN_B ((NN + 255) / 256)   // 391 blocks
#define NGRP 8
#define GSZ (NN / NGRP)             // 12500 exactly
#define BPG 128                     // blocks per group
#define NTILE ((NN + 63) / 64)      // 1563 row tiles

typedef __attribute__((ext_vector_type(8))) __bf16 bf16x8;
typedef __attribute__((ext_vector_type(4))) float floatx4;
typedef __attribute__((ext_vector_type(4))) unsigned short ushortx4;
typedef __attribute__((ext_vector_type(8))) unsigned short ushortx8;

static __device__ __forceinline__ unsigned short f2bf(float x) {
    union { float f; unsigned u; } v; v.f = x;
    unsigned r = v.u + 0x7fffu + ((v.u >> 16) & 1u);   // RNE
    return (unsigned short)(r >> 16);
}
static __device__ __forceinline__ float bflo(unsigned w) {
    union { unsigned u; float f; } v; v.u = w << 16; return v.f;
}
static __device__ __forceinline__ float bfhi(unsigned w) {
    union { unsigned u; float f; } v; v.u = w & 0xffff0000u; return v.f;
}

// fp32 -> bf16 (vectorized by 4)
__global__ void k_convert(const float* __restrict__ s, unsigned short* __restrict__ d, int n4) {
    int i = blockIdx.x * blockDim.x + threadIdx.x;
    if (i < n4) {
        floatx4 f = __builtin_nontemporal_load((const floatx4*)s + i);
        ushortx4 o;
        o.x = f2bf(f.x); o.y = f2bf(f.y); o.z = f2bf(f.z); o.w = f2bf(f.w);
        __builtin_nontemporal_store(o, (ushortx4*)d + i);
    }
}

// Build W2t: [n][k] bf16, k in 0..255 = [Wv ; Wu], 16B k-chunks XOR-swizzled
// (chunk kg stored at position kg ^ (n&7)) so k_gemm stages linearly and
// reads conflict-free.
__global__ void k_prep(const float* __restrict__ wv, const float* __restrict__ wu,
                       unsigned short* __restrict__ w2t) {
    int id = blockIdx.x * 256 + threadIdx.x;   // 0..4095
    if (id >= 128 * 32) return;
    int n = id >> 5, kg = id & 31;
    const float* srcm = (kg < 16) ? wv : wu;
    int k0 = (kg & 15) * 8;
    ushortx8 o;
#pragma unroll
    for (int j = 0; j < 8; ++j)
        o[j] = f2bf(srcm[(k0 + j) * 128 + n]);
    int dchunk = n * 32 + (kg ^ (n & 7));
    *(ushortx8*)(w2t + dchunk * 8) = o;
}

// degree count, dst-range partitioned: atomics stay in one XCD's L2 slice
__global__ void k_deg(const int* __restrict__ dst, int* __restrict__ deg) {
    int base = (blockIdx.x & (NGRP - 1)) * GSZ;
    int tid = (blockIdx.x >> 3) * 256 + threadIdx.x;
    for (int i = tid; i < NE; i += BPG * 256) {
        int d = __builtin_nontemporal_load(&dst[i]);
        if ((unsigned)(d - base) < (unsigned)GSZ) atomicAdd(&deg[d], 1);
    }
}

// phase A: per-block exclusive scan of 256 elements; emit block sums
__global__ void k_scan_a(const int* __restrict__ deg, int* __restrict__ offs,
                         int* __restrict__ bsums) {
    __shared__ int sh[256];
    int i = blockIdx.x * 256 + threadIdx.x;
    int v = (i < NN) ? deg[i] : 0;
    sh[threadIdx.x] = v;
    __syncthreads();
    for (int off = 1; off < 256; off <<= 1) {
        int u = (threadIdx.x >= off) ? sh[threadIdx.x - off] : 0;
        __syncthreads();
        sh[threadIdx.x] += u;
        __syncthreads();
    }
    if (i < NN) offs[i] = sh[threadIdx.x] - v;
    if (threadIdx.x == 255) bsums[blockIdx.x] = sh[255];
}

// phase B: single-block exclusive scan of the 391 block sums
__global__ void k_scan_b(int* __restrict__ bsums) {
    __shared__ int sh[512];
    int t = threadIdx.x;
    int v = (t < SCAN_B) ? bsums[t] : 0;
    sh[t] = v;
    __syncthreads();
    for (int off = 1; off < 512; off <<= 1) {
        int u = (t >= off) ? sh[t - off] : 0;
        __syncthreads();
        sh[t] += u;
        __syncthreads();
    }
    if (t < SCAN_B) bsums[t] = sh[t] - v;
    if (t == SCAN_B - 1) bsums[SCAN_B] = sh[t];
}

// phase C: add block prefix, materialize offs + cursor
__global__ void k_scan_c(int* __restrict__ offs, int* __restrict__ cursor,
                         const int* __restrict__ bsums) {
    int i = blockIdx.x * 256 + threadIdx.x;
    if (i < NN) {
        int o = offs[i] + bsums[blockIdx.x];
        offs[i] = o;
        cursor[i] = o;
    }
    if (i == NN - 1) offs[NN] = bsums[SCAN_B];
}

// CSR scatter, dst-range partitioned for L2-local writes
__global__ void k_scatter(const int* __restrict__ src, const int* __restrict__ dst,
                          int* __restrict__ cursor, int* __restrict__ csr) {
    int base = (blockIdx.x & (NGRP - 1)) * GSZ;
    int tid = (blockIdx.x >> 3) * 256 + threadIdx.x;
    for (int i = tid; i < NE; i += BPG * 256) {
        int d = __builtin_nontemporal_load(&dst[i]);
        if ((unsigned)(d - base) < (unsigned)GSZ) {
            int s = __builtin_nontemporal_load(&src[i]);
            int p = atomicAdd(&cursor[d], 1);
            csr[p] = s;
        }
    }
}

// one wave per node: fp32 accumulate of bf16 feat rows, scale by 1/max(deg,1),
// write bf16 agg row (norm folded in so the GEMM is a single K=256 matmul)
__global__ void k_aggregate(const unsigned short* __restrict__ featb,
                            const int* __restrict__ offs,
                            const int* __restrict__ csr,
                            unsigned short* __restrict__ aggb) {
    int lane = threadIdx.x & 63;
    int node = blockIdx.x * 4 + (threadIdx.x >> 6);
    if (node >= NN) return;
    int s0 = offs[node], s1 = offs[node + 1];
    float a0 = 0.f, a1 = 0.f;
    for (int base = s0; base < s1; base += 64) {
        int e = (base + lane < s1) ? csr[base + lane] : 0;
        int m = s1 - base; if (m > 64) m = 64;
        int j = 0;
        for (; j + 8 <= m; j += 8) {                    // 8 loads in flight
            unsigned w0 = *(const unsigned*)(featb + (size_t)__shfl(e, j + 0, 64) * NF + lane * 2);
            unsigned w1 = *(const unsigned*)(featb + (size_t)__shfl(e, j + 1, 64) * NF + lane * 2);
            unsigned w2 = *(const unsigned*)(featb + (size_t)__shfl(e, j + 2, 64) * NF + lane * 2);
            unsigned w3 = *(const unsigned*)(featb + (size_t)__shfl(e, j + 3, 64) * NF + lane * 2);
            unsigned w4 = *(const unsigned*)(featb + (size_t)__shfl(e, j + 4, 64) * NF + lane * 2);
            unsigned w5 = *(const unsigned*)(featb + (size_t)__shfl(e, j + 5, 64) * NF + lane * 2);
            unsigned w6 = *(const unsigned*)(featb + (size_t)__shfl(e, j + 6, 64) * NF + lane * 2);
            unsigned w7 = *(const unsigned*)(featb + (size_t)__shfl(e, j + 7, 64) * NF + lane * 2);
            a0 += bflo(w0) + bflo(w1) + bflo(w2) + bflo(w3)
                + bflo(w4) + bflo(w5) + bflo(w6) + bflo(w7);
            a1 += bfhi(w0) + bfhi(w1) + bfhi(w2) + bfhi(w3)
                + bfhi(w4) + bfhi(w5) + bfhi(w6) + bfhi(w7);
        }
        for (; j < m; ++j) {
            int nn = __shfl(e, j, 64);
            unsigned w = *(const unsigned*)(featb + (size_t)nn * NF + lane * 2);
            a0 += bflo(w); a1 += bfhi(w);
        }
    }
    int dg = s1 - s0; if (dg < 1) dg = 1;
    float scale = 1.0f / (float)dg;
    unsigned outw = ((unsigned)f2bf(a1 * scale) << 16) | (unsigned)f2bf(a0 * scale);
    *(unsigned*)(aggb + (size_t)node * NF + lane * 2) = outw;
}

// single fused GEMM: out = relu([feat | agg_n] @ W2 + bias), K=256
// persistent grid-stride over 64-row tiles; weights staged once per block
__global__ __launch_bounds__(256, 2) void k_gemm(
    const unsigned short* __restrict__ featb,   // [NN,128] bf16
    const unsigned short* __restrict__ aggb,    // [NN,128] bf16 (norm-scaled)
    const unsigned short* __restrict__ w2t,     // [128][256] bf16, swizzled
    const float* __restrict__ bias,
    float* __restrict__ out) {
    __shared__ unsigned short lds[128 * 256];   // 64 KiB
    for (int i = threadIdx.x; i < 4096; i += 256) {   // linear b128 copy
        ushortx8 w = *(const ushortx8*)(w2t + i * 8);
        *(ushortx8*)(&lds[i * 8]) = w;
    }
    __syncthreads();

    int lane = threadIdx.x & 63;
    int wave = threadIdx.x >> 6;
    int quad = lane >> 4, l15 = lane & 15;

    float bsv[8];
#pragma unroll
    for (int ct = 0; ct < 8; ++ct) bsv[ct] = bias[ct * 16 + l15];

    for (int t = blockIdx.x; t < NTILE; t += gridDim.x) {
        int rb = t * 64 + wave * 16;
        int arow = rb + l15; if (arow > NN - 1) arow = NN - 1;
        const unsigned short* fr = featb + (size_t)arow * NF;
        const unsigned short* ar = aggb + (size_t)arow * NF;
        bf16x8 a[8];
#pragma unroll
        for (int ks = 0; ks < 4; ++ks) {
            a[ks]     = *(const bf16x8*)(fr + ks * 32 + quad * 8);
            a[4 + ks] = *(const bf16x8*)(ar + ks * 32 + quad * 8);
        }
        floatx4 acc[8];
#pragma unroll
        for (int ct = 0; ct < 8; ++ct) acc[ct] = (floatx4){0.f, 0.f, 0.f, 0.f};
#pragma unroll
        for (int ct = 0; ct < 8; ++ct) {
            int n = ct * 16 + l15;
            int rowoff = n << 8;
            int sw = n & 7;
#pragma unroll
            for (int ks = 0; ks < 8; ++ks) {
                int kg = ks * 4 + quad;
                bf16x8 b = *(const bf16x8*)(&lds[rowoff + ((kg ^ sw) << 3)]);
                acc[ct] = __builtin_amdgcn_mfma_f32_16x16x32_bf16(a[ks], b, acc[ct], 0, 0, 0);
            }
        }
#pragma unroll
        for (int ct = 0; ct < 8; ++ct) {
            int col = ct * 16 + l15;
#pragma unroll
            for (int r = 0; r < 4; ++r) {
                int row = rb + quad * 4 + r;
                if (row < NN) {
                    float v = acc[ct][r] + bsv[ct];
                    out[(size_t)row * NF + col] = v > 0.f ? v : 0.f;
                }
            }
        }
    }
}

extern "C" void kernel_launch(void* const* d_in, const int* in_sizes, int n_in,
                              void* d_out, int out_size, void* d_ws, size_t ws_size,
                              hipStream_t stream) {
    const float* feat = (const float*)d_in[0];
    const float* wu   = (const float*)d_in[1];
    const float* wv   = (const float*)d_in[2];
    const float* bias = (const float*)d_in[3];
    const int* src    = (const int*)d_in[4];
    const int* dst    = (const int*)d_in[5];
    float* out        = (float*)d_out;

    char* ws = (char*)d_ws;
    int* deg              = (int*)(ws + 0);                 //   400,000 B
    int* offs             = (int*)(ws + 400384);            //   400,004 B
    int* cursor           = (int*)(ws + 800768);            //   400,000 B
    int* csr              = (int*)(ws + 1201152);           // 6,400,000 B
    unsigned short* featb = (unsigned short*)(ws + 7601152);   // 25,600,000 B
    unsigned short* aggb  = (unsigned short*)(ws + 33201152);  // 25,600,000 B
    unsigned short* w2t   = (unsigned short*)(ws + 58801152);  //    65,536 B
    // bsums aliases aggb's region: dead before k_aggregate writes aggb
    int* bsums            = (int*)aggb;                     // (SCAN_B+1) ints

    hipMemsetAsync(deg, 0, NN * sizeof(int), stream);

    k_convert<<<(NN * NF / 4 + 255) / 256, 256, 0, stream>>>(feat, featb, NN * NF / 4);
    k_prep<<<16, 256, 0, stream>>>(wv, wu, w2t);

    k_deg<<<NGRP * BPG, 256, 0, stream>>>(dst, deg);
    k_scan_a<<<SCAN_B, 256, 0, stream>>>(deg, offs, bsums);
    k_scan_b<<<1, 512, 0, stream>>>(bsums);
    k_scan_c<<<SCAN_B, 256, 0, stream>>>(offs, cursor, bsums);
    k_scatter<<<NGRP * BPG, 256, 0, stream>>>(src, dst, cursor, csr);
    k_aggregate<<<(NN + 3) / 4, 256, 0, stream>>>(featb, offs, csr, aggb);
    k_gemm<<<768, 256, 0, stream>>>(featb, aggb, w2t, bias, out);
}